// Round 6
// baseline (247.690 us; speedup 1.0000x reference)
//
#include <hip/hip_runtime.h>
#include <hip/hip_bf16.h>

typedef unsigned short u16;
typedef __attribute__((ext_vector_type(4))) float f32x4;
typedef __attribute__((ext_vector_type(16))) float f32x16;
typedef __attribute__((ext_vector_type(8))) short bf16x8;
typedef __attribute__((ext_vector_type(4))) short short4v;

#define B_N 8192
#define D_N 8000
#define H_N 100
#define V_N 8000
#define NG  512    // padded 4H
#define NKT 256    // K-steps of 32: 8192 total K (8000 x + 100 hidden + 92 pad)
#define TW  192    // tail width (hidden 100 + 92 zeros)

typedef const __attribute__((address_space(1))) unsigned int* gp_t;
typedef __attribute__((address_space(3))) unsigned int* lp_t;

static __device__ __forceinline__ short f2bf(float f) {
  unsigned u;
  __builtin_memcpy(&u, &f, 4);
  u = (u + 0x7fffu + ((u >> 16) & 1u)) >> 16;   // RNE
  return (short)u;
}
static __device__ __forceinline__ float bf2f(u16 b) {
  unsigned u = ((unsigned)b) << 16;
  float f;
  __builtin_memcpy(&f, &u, 4);
  return f;
}

// ---------------- pack hidden -> tail f32 [B_N][TW] (hidden | zeros) --------
__global__ __launch_bounds__(256) void pack_tail_kernel(
    const float* __restrict__ hidden, float* __restrict__ tail) {
  int idx = blockIdx.x * 256 + threadIdx.x;       // over B_N*24 chunks of 8
  if (idx >= B_N * 24) return;
  int b = idx / 24, c8 = (idx - b * 24) * 8;
  float o[8];
  if (c8 + 8 <= H_N) {
    const float* ph = hidden + (size_t)b * H_N + c8;
#pragma unroll
    for (int j = 0; j < 8; ++j) o[j] = ph[j];
  } else {
#pragma unroll
    for (int j = 0; j < 8; ++j) {
      int c = c8 + j;
      o[j] = (c < H_N) ? hidden[(size_t)b * H_N + c] : 0.f;
    }
  }
  f32x4 v0, v1;
#pragma unroll
  for (int j = 0; j < 4; ++j) { v0[j] = o[j]; v1[j] = o[4 + j]; }
  *(f32x4*)(tail + (size_t)b * TW + c8) = v0;
  *(f32x4*)(tail + (size_t)b * TW + c8 + 4) = v1;
}

// ---------------- pack U|W -> Wc, gld-linear physical order -----------------
__global__ __launch_bounds__(256) void pack_w_kernel(
    const float* __restrict__ U0, const float* __restrict__ U1,
    const float* __restrict__ U2, const float* __restrict__ U3,
    const float* __restrict__ W0, const float* __restrict__ W1,
    const float* __restrict__ W2, const float* __restrict__ W3,
    u16* __restrict__ Wc) {
  int idx = blockIdx.x * 256 + threadIdx.x;
  if (idx >= NKT * 2048) return;
  int t = idx >> 11;
  int j = idx & 2047;
  int pair = j >> 3, p = j & 7;
  int pl = p ^ (pair & 7);
  int n = pair * 2 + (pl >> 2);
  int s = pl & 3;
  int k0 = t * 32 + s * 8;
  bf16x8 ov;
  if (n >= 400) {
#pragma unroll
    for (int e = 0; e < 8; ++e) ov[e] = 0;
  } else {
    int g = n / 100;
    int r = n - g * 100;
    const float* U = (g == 0) ? U0 : (g == 1) ? U1 : (g == 2) ? U2 : U3;
    const float* W = (g == 0) ? W0 : (g == 1) ? W1 : (g == 2) ? W2 : W3;
    if (k0 + 8 <= D_N) {
      const float* pu = U + (size_t)r * D_N + k0;
      f32x4 v0 = *(const f32x4*)pu;
      f32x4 v1 = *(const f32x4*)(pu + 4);
#pragma unroll
      for (int e = 0; e < 4; ++e) { ov[e] = f2bf(v0[e]); ov[4 + e] = f2bf(v1[e]); }
    } else {
#pragma unroll
      for (int e = 0; e < 8; ++e) {
        int col = k0 + e - D_N;
        ov[e] = (col >= 0 && col < H_N) ? f2bf(W[(size_t)r * H_N + col]) : (short)0;
      }
    }
  }
  *(bf16x8*)(Wc + (size_t)idx * 8) = ov;
}

// ---------------- pack V_w -> V2, MFMA-native layout ------------------------
__global__ __launch_bounds__(256) void pack_vw_kernel(
    const float* __restrict__ Vw, u16* __restrict__ V2) {
  int idx = blockIdx.x * 256 + threadIdx.x;
  if (idx >= 500 * 256) return;
  int n16 = idx >> 8, r = idx & 255;
  int kk = r >> 6, q = r & 63;
  int h = q >> 4, lr = q & 15;
  int n = n16 * 16 + lr;
  int k0 = kk * 32 + h * 8;
  bf16x8 ov;
#pragma unroll
  for (int e = 0; e < 8; ++e) {
    int col = k0 + e;
    ov[e] = (col < H_N) ? f2bf(Vw[(size_t)n * H_N + col]) : (short)0;
  }
  *(bf16x8*)(V2 + (size_t)idx * 8) = ov;
}

// ---------------- gates GEMM: BM=64, BN=512, BK=32, splitK=4 ----------------
// XCD-aware decode: all blocks on one XCD share a single kz quarter of Wc
// (2.1 MB -> fits 4 MB per-XCD L2, kills the 1 GB L3 re-read stream).
__global__ __launch_bounds__(512, 4) void gates_gemm_kernel(
    const float* __restrict__ x, const float* __restrict__ tail,
    const u16* __restrict__ Wc, u16* __restrict__ Cp) {
  __shared__ __align__(16) u16 As[2][2048];     // 4 KB each, pair-XOR swizzled
  __shared__ __align__(16) u16 Bs[2][16384];    // 32 KB each, pre-swizzled src
  const int t = threadIdx.x;
  const int w = t >> 6, l = t & 63;
  const int bid = blockIdx.x;
  const int xcd = bid & 7;
  const int kz = xcd >> 1;
  const int bm = (bid >> 3) | ((xcd & 1) << 6);   // 0..127, bijective with kz
  const int t0 = kz * 64;
  const int tmax = t0 + 63;

  const int arow = t >> 3, ao = t & 7;
  const float* xrow = x + (size_t)(bm * 64 + arow) * D_N + ao * 4;
  const float* trow = tail + (size_t)(bm * 64 + arow) * TW + ao * 4;
  const int apair = arow >> 1;
  const int awr = apair * 64 + ((((arow & 1) << 2) | (ao >> 1)) ^ (apair & 7)) * 8
                  + (ao & 1) * 4;  // u16 units

  const int wn = w * 64;
  int aoff[2][2], boff[2][2];
#pragma unroll
  for (int kk = 0; kk < 2; ++kk)
#pragma unroll
    for (int i = 0; i < 2; ++i) {
      int rowa = i * 32 + (l & 31);
      int sa = kk * 2 + (l >> 5);
      int pa = rowa >> 1;
      aoff[kk][i] = pa * 64 + ((((rowa & 1) << 2) | sa) ^ (pa & 7)) * 8;
      int rowb = wn + i * 32 + (l & 31);
      int pb = rowb >> 1;
      boff[kk][i] = pb * 64 + ((((rowb & 1) << 2) | sa) ^ (pb & 7)) * 8;
    }

  f32x16 acc00 = (f32x16)0.f, acc01 = (f32x16)0.f;
  f32x16 acc10 = (f32x16)0.f, acc11 = (f32x16)0.f;

#define ASRC(tt) ((tt) < 250 ? xrow + (size_t)(tt) * 32 : trow + (size_t)((tt) - 250) * 32)
#define GLD_B(tt, buf)                                                         \
  _Pragma("unroll") for (int q = 0; q < 4; ++q)                                \
      __builtin_amdgcn_global_load_lds(                                        \
          (gp_t)(const void*)(Wc + ((size_t)(tt) * 2048 + t + q * 512) * 8),   \
          (lp_t)(void*)((u16*)Bs[buf] + (t + q * 512) * 8), 16, 0, 0);
#define DSW_A(buf, rv)                                                         \
  {                                                                            \
    short4v wv;                                                                \
    wv[0] = f2bf(rv[0]); wv[1] = f2bf(rv[1]);                                  \
    wv[2] = f2bf(rv[2]); wv[3] = f2bf(rv[3]);                                  \
    *(short4v*)((u16*)As[buf] + awr) = wv;                                     \
  }
#define COMPUTE(buf)                                                           \
  _Pragma("unroll") for (int kk = 0; kk < 2; ++kk) {                           \
    bf16x8 af0 = *(const bf16x8*)((const u16*)As[buf] + aoff[kk][0]);          \
    bf16x8 af1 = *(const bf16x8*)((const u16*)As[buf] + aoff[kk][1]);          \
    bf16x8 bv0 = *(const bf16x8*)((const u16*)Bs[buf] + boff[kk][0]);          \
    bf16x8 bv1 = *(const bf16x8*)((const u16*)Bs[buf] + boff[kk][1]);          \
    acc00 = __builtin_amdgcn_mfma_f32_32x32x16_bf16(af0, bv0, acc00, 0, 0, 0); \
    acc01 = __builtin_amdgcn_mfma_f32_32x32x16_bf16(af0, bv1, acc01, 0, 0, 0); \
    acc10 = __builtin_amdgcn_mfma_f32_32x32x16_bf16(af1, bv0, acc10, 0, 0, 0); \
    acc11 = __builtin_amdgcn_mfma_f32_32x32x16_bf16(af1, bv1, acc11, 0, 0, 0); \
  }
#define BODY(CB, SUSE, SDEF, tc)                                               \
  {                                                                            \
    __builtin_amdgcn_s_barrier();                                              \
    int tb = (tc) + 1 > tmax ? tmax : (tc) + 1;                                \
    GLD_B(tb, (CB) ^ 1);                                                       \
    int ta = (tc) + 4 > tmax ? tmax : (tc) + 4;                                \
    SDEF = *(const f32x4*)ASRC(ta);                                            \
    __builtin_amdgcn_sched_barrier(0);                                         \
    asm volatile("s_waitcnt vmcnt(6)" ::: "memory");                           \
    __builtin_amdgcn_sched_barrier(0);                                         \
    DSW_A((CB) ^ 1, SUSE);                                                     \
    asm volatile("s_waitcnt lgkmcnt(0)" ::: "memory");                         \
    __builtin_amdgcn_s_barrier();                                              \
    __builtin_amdgcn_sched_barrier(0);                                         \
    COMPUTE(CB);                                                               \
  }

  f32x4 s0, s1, s2, s3;
  {
    f32x4 r0 = *(const f32x4*)ASRC(t0);
    asm volatile("s_waitcnt vmcnt(0)" ::: "memory");
    DSW_A(0, r0);
  }
  GLD_B(t0, 0);
  __builtin_amdgcn_sched_barrier(0);
  s0 = *(const f32x4*)ASRC(t0 + 1);
  s1 = *(const f32x4*)ASRC(t0 + 2);
  s2 = *(const f32x4*)ASRC(t0 + 3);
  __builtin_amdgcn_sched_barrier(0);

  for (int tt = t0; tt < t0 + 64; tt += 4) {
    BODY(0, s0, s3, tt);
    BODY(1, s1, s0, tt + 1);
    BODY(0, s2, s1, tt + 2);
    BODY(1, s3, s2, tt + 3);
  }

  // epilogue: store acc to bf16 partial buffer kz
  u16* Cg = Cp + (size_t)kz * B_N * NG;
  const int lcol = l & 31, lhi = (l >> 5) * 4;
#pragma unroll
  for (int mi = 0; mi < 2; ++mi)
#pragma unroll
    for (int ni = 0; ni < 2; ++ni) {
      f32x16 a = (mi == 0) ? (ni == 0 ? acc00 : acc01)
                           : (ni == 0 ? acc10 : acc11);
#pragma unroll
      for (int reg = 0; reg < 16; ++reg) {
        int row = bm * 64 + mi * 32 + (reg & 3) + 8 * (reg >> 2) + lhi;
        Cg[(size_t)row * NG + wn + ni * 32 + lcol] = (u16)f2bf(a[reg]);
      }
    }
#undef BODY
#undef COMPUTE
#undef DSW_A
#undef GLD_B
#undef ASRC
}

// ---------------- fused act + logits + log_softmax --------------------------
// Block = 16 rows, 512 thr (8 waves), grid 512 -> 2 blocks/CU so one block's
// pass-2 write stream overlaps the other's pass-1 compute. Phase0: LSTM
// pointwise for 16 rows; 2-pass fixed-shift logsumexp over V.
__global__ __launch_bounds__(512, 4) void logits_lsm_kernel(
    const u16* __restrict__ gp, const float* __restrict__ c_in,
    const float* __restrict__ biu, const float* __restrict__ bfu,
    const float* __restrict__ bou, const float* __restrict__ bgu,
    const float* __restrict__ biw, const float* __restrict__ bfw,
    const float* __restrict__ bow, const float* __restrict__ bgw,
    const u16* __restrict__ V2, const float* __restrict__ Vb,
    float* __restrict__ h_out, float* __restrict__ c_out,
    float* __restrict__ out) {
  __shared__ u16 hs[16][128];
  __shared__ float red[8][16];
  __shared__ float lse_s[16];
  int t = threadIdx.x, w = t >> 6, l = t & 63;
  int lr = l & 15, hq = l >> 4;
  int rowbase = blockIdx.x * 16;

  // ---- phase 0: LSTM pointwise for our 16 rows ----
  if (t < 16 * 28) hs[t / 28][100 + t % 28] = 0;
  const size_t st = (size_t)B_N * NG;
  for (int i = t; i < 1600; i += 512) {
    int b = i / 100, r = i - b * 100;
    int row = rowbase + b;
    const u16* g0 = gp + (size_t)row * NG;
    float gi = bf2f(g0[r]) + bf2f(g0[r + st]) + bf2f(g0[r + 2 * st]) +
               bf2f(g0[r + 3 * st]) + biu[r] + biw[r];
    float gf = bf2f(g0[r + 100]) + bf2f(g0[r + 100 + st]) +
               bf2f(g0[r + 100 + 2 * st]) + bf2f(g0[r + 100 + 3 * st]) +
               bfu[r] + bfw[r];
    float go = bf2f(g0[r + 200]) + bf2f(g0[r + 200 + st]) +
               bf2f(g0[r + 200 + 2 * st]) + bf2f(g0[r + 200 + 3 * st]) +
               bou[r] + bow[r];
    float gg = bf2f(g0[r + 300]) + bf2f(g0[r + 300 + st]) +
               bf2f(g0[r + 300 + 2 * st]) + bf2f(g0[r + 300 + 3 * st]) +
               bgu[r] + bgw[r];
    float it = 1.f / (1.f + __expf(-gi));
    float ft = 1.f / (1.f + __expf(-gf));
    float ot = 1.f / (1.f + __expf(-go));
    float gt = tanhf(gg);
    float ct = c_in[(size_t)row * H_N + r] * ft + gt * it;
    float ht = tanhf(ct) * ot;
    h_out[(size_t)row * H_N + r] = ht;
    c_out[(size_t)row * H_N + r] = ct;
    hs[b][r] = (u16)f2bf(ht);
  }
  __syncthreads();

  bf16x8 hf[4];
#pragma unroll
  for (int kk = 0; kk < 4; ++kk)
    hf[kk] = *(const bf16x8*)(&hs[lr][kk * 32 + hq * 8]);

  float s[4];
#pragma unroll
  for (int r = 0; r < 4; ++r) s[r] = 0.f;

  // ---- pass 1: sum of exp(logit - 8) ----
  for (int c = 0; c < 16; ++c) {
    int colbase = c * 512 + w * 64;
    if (colbase >= V_N) continue;
    int n16b = colbase >> 4;
    f32x4 acc[4];
#pragma unroll
    for (int ni = 0; ni < 4; ++ni) acc[ni] = (f32x4)0.f;
#pragma unroll
    for (int ni = 0; ni < 4; ++ni)
#pragma unroll
      for (int kk = 0; kk < 4; ++kk) {
        bf16x8 vf = *(const bf16x8*)(V2 +
            (((size_t)(n16b + ni) * 4 + kk) * 64 + l) * 8);
        acc[ni] = __builtin_amdgcn_mfma_f32_16x16x32_bf16(
            hf[kk], vf, acc[ni], 0, 0, 0);
      }
    float vb[4];
#pragma unroll
    for (int ni = 0; ni < 4; ++ni) vb[ni] = Vb[colbase + ni * 16 + lr];
#pragma unroll
    for (int j = 0; j < 4; ++j) {
      float e = 0.f;
#pragma unroll
      for (int ni = 0; ni < 4; ++ni)
        e += __expf(acc[ni][j] + vb[ni] - 8.f);
      s[j] += e;
    }
  }
#pragma unroll
  for (int off = 1; off < 16; off <<= 1)
#pragma unroll
    for (int r = 0; r < 4; ++r) s[r] += __shfl_xor(s[r], off, 64);

  if (lr == 0) {
#pragma unroll
    for (int r = 0; r < 4; ++r) red[w][hq * 4 + r] = s[r];
  }
  __syncthreads();
  if (t < 16) {
    float S = 0.f;
#pragma unroll
    for (int ww = 0; ww < 8; ++ww) S += red[ww][t];
    lse_s[t] = 8.f + __logf(S);
  }
  __syncthreads();
  float lse_r[4];
#pragma unroll
  for (int r = 0; r < 4; ++r) lse_r[r] = lse_s[hq * 4 + r];

  // ---- pass 2: recompute, subtract, store ----
  for (int c = 0; c < 16; ++c) {
    int colbase = c * 512 + w * 64;
    if (colbase >= V_N) continue;
    int n16b = colbase >> 4;
    f32x4 acc[4];
#pragma unroll
    for (int ni = 0; ni < 4; ++ni) acc[ni] = (f32x4)0.f;
#pragma unroll
    for (int ni = 0; ni < 4; ++ni)
#pragma unroll
      for (int kk = 0; kk < 4; ++kk) {
        bf16x8 vf = *(const bf16x8*)(V2 +
            (((size_t)(n16b + ni) * 4 + kk) * 64 + l) * 8);
        acc[ni] = __builtin_amdgcn_mfma_f32_16x16x32_bf16(
            hf[kk], vf, acc[ni], 0, 0, 0);
      }
    float vb[4];
#pragma unroll
    for (int ni = 0; ni < 4; ++ni) vb[ni] = Vb[colbase + ni * 16 + lr];
#pragma unroll
    for (int j = 0; j < 4; ++j) {
      size_t gr = (size_t)(rowbase + hq * 4 + j);
#pragma unroll
      for (int ni = 0; ni < 4; ++ni)
        out[gr * V_N + colbase + ni * 16 + lr] =
            acc[ni][j] + vb[ni] - lse_r[j];
    }
  }
}

extern "C" void kernel_launch(void* const* d_in, const int* in_sizes, int n_in,
                              void* d_out, int out_size, void* d_ws,
                              size_t ws_size, hipStream_t stream) {
  const float* x      = (const float*)d_in[0];
  const float* hidden = (const float*)d_in[1];
  const float* c_in   = (const float*)d_in[2];
  const float* Ui = (const float*)d_in[3];
  const float* Uf = (const float*)d_in[4];
  const float* Uo = (const float*)d_in[5];
  const float* Ug = (const float*)d_in[6];
  const float* Wi = (const float*)d_in[7];
  const float* Wf = (const float*)d_in[8];
  const float* Wo = (const float*)d_in[9];
  const float* Wg = (const float*)d_in[10];
  const float* Vw = (const float*)d_in[11];
  const float* Uib = (const float*)d_in[12];
  const float* Ufb = (const float*)d_in[13];
  const float* Uob = (const float*)d_in[14];
  const float* Ugb = (const float*)d_in[15];
  const float* Wib = (const float*)d_in[16];
  const float* Wfb = (const float*)d_in[17];
  const float* Wob = (const float*)d_in[18];
  const float* Wgb = (const float*)d_in[19];
  const float* Vb  = (const float*)d_in[20];

  float* out   = (float*)d_out;
  float* h_out = out + (size_t)B_N * V_N;
  float* c_out = h_out + (size_t)B_N * H_N;

  char* ws = (char*)d_ws;
  float* tailf = (float*)ws;  ws += (size_t)B_N * TW * 4;        // 6.3 MB
  u16* Wc = (u16*)ws;         ws += (size_t)NKT * 2048 * 16;     // 8.4 MB
  u16* V2 = (u16*)ws;         ws += (size_t)500 * 256 * 16;      // 2.0 MB
  u16* gates_p = (u16*)ws;    ws += (size_t)4 * B_N * NG * 2;    // 33.6 MB

  pack_tail_kernel<<<dim3(768), dim3(256), 0, stream>>>(hidden, tailf);
  pack_w_kernel<<<dim3(2048), dim3(256), 0, stream>>>(Ui, Uf, Uo, Ug,
                                                      Wi, Wf, Wo, Wg, Wc);
  pack_vw_kernel<<<dim3(500), dim3(256), 0, stream>>>(Vw, V2);

  gates_gemm_kernel<<<dim3(512), dim3(512), 0, stream>>>(
      x, tailf, Wc, gates_p);

  logits_lsm_kernel<<<dim3(512), dim3(512), 0, stream>>>(
      gates_p, c_in, Uib, Ufb, Uob, Ugb, Wib, Wfb, Wob, Wgb,
      V2, Vb, h_out, c_out, out);
}

// Round 7
// 221.398 us; speedup vs baseline: 1.1188x; 1.1188x over previous
//
#include <hip/hip_runtime.h>
#include <hip/hip_bf16.h>

typedef unsigned short u16;
typedef __attribute__((ext_vector_type(4))) float f32x4;
typedef __attribute__((ext_vector_type(16))) float f32x16;
typedef __attribute__((ext_vector_type(8))) short bf16x8;
typedef __attribute__((ext_vector_type(4))) short short4v;

#define B_N 8192
#define D_N 8000
#define H_N 100
#define V_N 8000
#define NG  512    // padded 4H
#define NKT 256    // K-steps of 32: 8192 total K (8000 x + 100 hidden + 92 pad)
#define TW  192    // tail width (hidden 100 + 92 zeros)

typedef const __attribute__((address_space(1))) unsigned int* gp_t;
typedef __attribute__((address_space(3))) unsigned int* lp_t;

static __device__ __forceinline__ short f2bf(float f) {
  unsigned u;
  __builtin_memcpy(&u, &f, 4);
  u = (u + 0x7fffu + ((u >> 16) & 1u)) >> 16;   // RNE
  return (short)u;
}
static __device__ __forceinline__ float bf2f(u16 b) {
  unsigned u = ((unsigned)b) << 16;
  float f;
  __builtin_memcpy(&f, &u, 4);
  return f;
}

// ---------------- pack hidden -> tail f32 [B_N][TW] (hidden | zeros) --------
__global__ __launch_bounds__(256) void pack_tail_kernel(
    const float* __restrict__ hidden, float* __restrict__ tail) {
  int idx = blockIdx.x * 256 + threadIdx.x;       // over B_N*24 chunks of 8
  if (idx >= B_N * 24) return;
  int b = idx / 24, c8 = (idx - b * 24) * 8;
  float o[8];
  if (c8 + 8 <= H_N) {
    const float* ph = hidden + (size_t)b * H_N + c8;
#pragma unroll
    for (int j = 0; j < 8; ++j) o[j] = ph[j];
  } else {
#pragma unroll
    for (int j = 0; j < 8; ++j) {
      int c = c8 + j;
      o[j] = (c < H_N) ? hidden[(size_t)b * H_N + c] : 0.f;
    }
  }
  f32x4 v0, v1;
#pragma unroll
  for (int j = 0; j < 4; ++j) { v0[j] = o[j]; v1[j] = o[4 + j]; }
  *(f32x4*)(tail + (size_t)b * TW + c8) = v0;
  *(f32x4*)(tail + (size_t)b * TW + c8 + 4) = v1;
}

// ---------------- pack U|W -> Wc, gld-linear physical order -----------------
__global__ __launch_bounds__(256) void pack_w_kernel(
    const float* __restrict__ U0, const float* __restrict__ U1,
    const float* __restrict__ U2, const float* __restrict__ U3,
    const float* __restrict__ W0, const float* __restrict__ W1,
    const float* __restrict__ W2, const float* __restrict__ W3,
    u16* __restrict__ Wc) {
  int idx = blockIdx.x * 256 + threadIdx.x;
  if (idx >= NKT * 2048) return;
  int t = idx >> 11;
  int j = idx & 2047;
  int pair = j >> 3, p = j & 7;
  int pl = p ^ (pair & 7);
  int n = pair * 2 + (pl >> 2);
  int s = pl & 3;
  int k0 = t * 32 + s * 8;
  bf16x8 ov;
  if (n >= 400) {
#pragma unroll
    for (int e = 0; e < 8; ++e) ov[e] = 0;
  } else {
    int g = n / 100;
    int r = n - g * 100;
    const float* U = (g == 0) ? U0 : (g == 1) ? U1 : (g == 2) ? U2 : U3;
    const float* W = (g == 0) ? W0 : (g == 1) ? W1 : (g == 2) ? W2 : W3;
    if (k0 + 8 <= D_N) {
      const float* pu = U + (size_t)r * D_N + k0;
      f32x4 v0 = *(const f32x4*)pu;
      f32x4 v1 = *(const f32x4*)(pu + 4);
#pragma unroll
      for (int e = 0; e < 4; ++e) { ov[e] = f2bf(v0[e]); ov[4 + e] = f2bf(v1[e]); }
    } else {
#pragma unroll
      for (int e = 0; e < 8; ++e) {
        int col = k0 + e - D_N;
        ov[e] = (col >= 0 && col < H_N) ? f2bf(W[(size_t)r * H_N + col]) : (short)0;
      }
    }
  }
  *(bf16x8*)(Wc + (size_t)idx * 8) = ov;
}

// ---------------- pack V_w -> V2, MFMA-native layout ------------------------
__global__ __launch_bounds__(256) void pack_vw_kernel(
    const float* __restrict__ Vw, u16* __restrict__ V2) {
  int idx = blockIdx.x * 256 + threadIdx.x;
  if (idx >= 500 * 256) return;
  int n16 = idx >> 8, r = idx & 255;
  int kk = r >> 6, q = r & 63;
  int h = q >> 4, lr = q & 15;
  int n = n16 * 16 + lr;
  int k0 = kk * 32 + h * 8;
  bf16x8 ov;
#pragma unroll
  for (int e = 0; e < 8; ++e) {
    int col = k0 + e;
    ov[e] = (col < H_N) ? f2bf(Vw[(size_t)n * H_N + col]) : (short)0;
  }
  *(bf16x8*)(V2 + (size_t)idx * 8) = ov;
}

// ---------------- gates GEMM: BM=64, BN=512, BK=32, splitK=4 ----------------
// XCD-aware decode: all blocks on one XCD share a single kz quarter of Wc.
__global__ __launch_bounds__(512, 4) void gates_gemm_kernel(
    const float* __restrict__ x, const float* __restrict__ tail,
    const u16* __restrict__ Wc, u16* __restrict__ Cp) {
  __shared__ __align__(16) u16 As[2][2048];     // 4 KB each, pair-XOR swizzled
  __shared__ __align__(16) u16 Bs[2][16384];    // 32 KB each, pre-swizzled src
  const int t = threadIdx.x;
  const int w = t >> 6, l = t & 63;
  const int bid = blockIdx.x;
  const int xcd = bid & 7;
  const int kz = xcd >> 1;
  const int bm = (bid >> 3) | ((xcd & 1) << 6);   // 0..127, bijective with kz
  const int t0 = kz * 64;
  const int tmax = t0 + 63;

  const int arow = t >> 3, ao = t & 7;
  const float* xrow = x + (size_t)(bm * 64 + arow) * D_N + ao * 4;
  const float* trow = tail + (size_t)(bm * 64 + arow) * TW + ao * 4;
  const int apair = arow >> 1;
  const int awr = apair * 64 + ((((arow & 1) << 2) | (ao >> 1)) ^ (apair & 7)) * 8
                  + (ao & 1) * 4;  // u16 units

  const int wn = w * 64;
  int aoff[2][2], boff[2][2];
#pragma unroll
  for (int kk = 0; kk < 2; ++kk)
#pragma unroll
    for (int i = 0; i < 2; ++i) {
      int rowa = i * 32 + (l & 31);
      int sa = kk * 2 + (l >> 5);
      int pa = rowa >> 1;
      aoff[kk][i] = pa * 64 + ((((rowa & 1) << 2) | sa) ^ (pa & 7)) * 8;
      int rowb = wn + i * 32 + (l & 31);
      int pb = rowb >> 1;
      boff[kk][i] = pb * 64 + ((((rowb & 1) << 2) | sa) ^ (pb & 7)) * 8;
    }

  f32x16 acc00 = (f32x16)0.f, acc01 = (f32x16)0.f;
  f32x16 acc10 = (f32x16)0.f, acc11 = (f32x16)0.f;

#define ASRC(tt) ((tt) < 250 ? xrow + (size_t)(tt) * 32 : trow + (size_t)((tt) - 250) * 32)
#define GLD_B(tt, buf)                                                         \
  _Pragma("unroll") for (int q = 0; q < 4; ++q)                                \
      __builtin_amdgcn_global_load_lds(                                        \
          (gp_t)(const void*)(Wc + ((size_t)(tt) * 2048 + t + q * 512) * 8),   \
          (lp_t)(void*)((u16*)Bs[buf] + (t + q * 512) * 8), 16, 0, 0);
#define DSW_A(buf, rv)                                                         \
  {                                                                            \
    short4v wv;                                                                \
    wv[0] = f2bf(rv[0]); wv[1] = f2bf(rv[1]);                                  \
    wv[2] = f2bf(rv[2]); wv[3] = f2bf(rv[3]);                                  \
    *(short4v*)((u16*)As[buf] + awr) = wv;                                     \
  }
#define COMPUTE(buf)                                                           \
  _Pragma("unroll") for (int kk = 0; kk < 2; ++kk) {                           \
    bf16x8 af0 = *(const bf16x8*)((const u16*)As[buf] + aoff[kk][0]);          \
    bf16x8 af1 = *(const bf16x8*)((const u16*)As[buf] + aoff[kk][1]);          \
    bf16x8 bv0 = *(const bf16x8*)((const u16*)Bs[buf] + boff[kk][0]);          \
    bf16x8 bv1 = *(const bf16x8*)((const u16*)Bs[buf] + boff[kk][1]);          \
    acc00 = __builtin_amdgcn_mfma_f32_32x32x16_bf16(af0, bv0, acc00, 0, 0, 0); \
    acc01 = __builtin_amdgcn_mfma_f32_32x32x16_bf16(af0, bv1, acc01, 0, 0, 0); \
    acc10 = __builtin_amdgcn_mfma_f32_32x32x16_bf16(af1, bv0, acc10, 0, 0, 0); \
    acc11 = __builtin_amdgcn_mfma_f32_32x32x16_bf16(af1, bv1, acc11, 0, 0, 0); \
  }
#define BODY(CB, SUSE, SDEF, tc)                                               \
  {                                                                            \
    __builtin_amdgcn_s_barrier();                                              \
    int tb = (tc) + 1 > tmax ? tmax : (tc) + 1;                                \
    GLD_B(tb, (CB) ^ 1);                                                       \
    int ta = (tc) + 4 > tmax ? tmax : (tc) + 4;                                \
    SDEF = *(const f32x4*)ASRC(ta);                                            \
    __builtin_amdgcn_sched_barrier(0);                                         \
    asm volatile("s_waitcnt vmcnt(6)" ::: "memory");                           \
    __builtin_amdgcn_sched_barrier(0);                                         \
    DSW_A((CB) ^ 1, SUSE);                                                     \
    asm volatile("s_waitcnt lgkmcnt(0)" ::: "memory");                         \
    __builtin_amdgcn_s_barrier();                                              \
    __builtin_amdgcn_sched_barrier(0);                                         \
    COMPUTE(CB);                                                               \
  }

  f32x4 s0, s1, s2, s3;
  {
    f32x4 r0 = *(const f32x4*)ASRC(t0);
    asm volatile("s_waitcnt vmcnt(0)" ::: "memory");
    DSW_A(0, r0);
  }
  GLD_B(t0, 0);
  __builtin_amdgcn_sched_barrier(0);
  s0 = *(const f32x4*)ASRC(t0 + 1);
  s1 = *(const f32x4*)ASRC(t0 + 2);
  s2 = *(const f32x4*)ASRC(t0 + 3);
  __builtin_amdgcn_sched_barrier(0);

  for (int tt = t0; tt < t0 + 64; tt += 4) {
    BODY(0, s0, s3, tt);
    BODY(1, s1, s0, tt + 1);
    BODY(0, s2, s1, tt + 2);
    BODY(1, s3, s2, tt + 3);
  }

  // epilogue: store acc to bf16 partial buffer kz
  u16* Cg = Cp + (size_t)kz * B_N * NG;
  const int lcol = l & 31, lhi = (l >> 5) * 4;
#pragma unroll
  for (int mi = 0; mi < 2; ++mi)
#pragma unroll
    for (int ni = 0; ni < 2; ++ni) {
      f32x16 a = (mi == 0) ? (ni == 0 ? acc00 : acc01)
                           : (ni == 0 ? acc10 : acc11);
#pragma unroll
      for (int reg = 0; reg < 16; ++reg) {
        int row = bm * 64 + mi * 32 + (reg & 3) + 8 * (reg >> 2) + lhi;
        Cg[(size_t)row * NG + wn + ni * 32 + lcol] = (u16)f2bf(a[reg]);
      }
    }
#undef BODY
#undef COMPUTE
#undef DSW_A
#undef GLD_B
#undef ASRC
}

// ---------------- fused act + logits + log_softmax --------------------------
// Block = 32 rows, 1024 thr (16 waves), grid 256. kk-outer double-buffered V
// fragments: working set 8 frags (32 VGPRs) instead of 16 (128) -> fits the
// 128-VGPR cap of a 1024-thread block without serializing loads.
__global__ __launch_bounds__(1024, 4) void logits_lsm_kernel(
    const u16* __restrict__ gp, const float* __restrict__ c_in,
    const float* __restrict__ biu, const float* __restrict__ bfu,
    const float* __restrict__ bou, const float* __restrict__ bgu,
    const float* __restrict__ biw, const float* __restrict__ bfw,
    const float* __restrict__ bow, const float* __restrict__ bgw,
    const u16* __restrict__ V2, const float* __restrict__ Vb,
    float* __restrict__ h_out, float* __restrict__ c_out,
    float* __restrict__ out) {
  __shared__ u16 hs[32][128];
  __shared__ float red[16][32];
  __shared__ float lse_s[32];
  int t = threadIdx.x, w = t >> 6, l = t & 63;
  int lr = l & 15, hq = l >> 4;
  int rowbase = blockIdx.x * 32;

  // ---- phase 0: LSTM pointwise for our 32 rows ----
  if (t < 32 * 28) hs[t / 28][100 + t % 28] = 0;
  const size_t st = (size_t)B_N * NG;
  for (int i = t; i < 3200; i += 1024) {
    int b = i / 100, r = i - b * 100;
    int row = rowbase + b;
    const u16* g0 = gp + (size_t)row * NG;
    float gi = bf2f(g0[r]) + bf2f(g0[r + st]) + bf2f(g0[r + 2 * st]) +
               bf2f(g0[r + 3 * st]) + biu[r] + biw[r];
    float gf = bf2f(g0[r + 100]) + bf2f(g0[r + 100 + st]) +
               bf2f(g0[r + 100 + 2 * st]) + bf2f(g0[r + 100 + 3 * st]) +
               bfu[r] + bfw[r];
    float go = bf2f(g0[r + 200]) + bf2f(g0[r + 200 + st]) +
               bf2f(g0[r + 200 + 2 * st]) + bf2f(g0[r + 200 + 3 * st]) +
               bou[r] + bow[r];
    float gg = bf2f(g0[r + 300]) + bf2f(g0[r + 300 + st]) +
               bf2f(g0[r + 300 + 2 * st]) + bf2f(g0[r + 300 + 3 * st]) +
               bgu[r] + bgw[r];
    float it = 1.f / (1.f + __expf(-gi));
    float ft = 1.f / (1.f + __expf(-gf));
    float ot = 1.f / (1.f + __expf(-go));
    float gt = tanhf(gg);
    float ct = c_in[(size_t)row * H_N + r] * ft + gt * it;
    float ht = tanhf(ct) * ot;
    h_out[(size_t)row * H_N + r] = ht;
    c_out[(size_t)row * H_N + r] = ct;
    hs[b][r] = (u16)f2bf(ht);
  }
  __syncthreads();

  bf16x8 hf[2][4];
#pragma unroll
  for (int mi = 0; mi < 2; ++mi)
#pragma unroll
    for (int kk = 0; kk < 4; ++kk)
      hf[mi][kk] = *(const bf16x8*)(&hs[mi * 16 + lr][kk * 32 + hq * 8]);

// vp points at this wave's 64-col group; frag (ni,kk) at vp + (ni*4+kk)*512
#define VLD(vp, ni, kk) (*(const bf16x8*)((vp) + ((ni) * 4 + (kk)) * 512))
#define MF(accv, buf, kk)                                                      \
  _Pragma("unroll") for (int ni = 0; ni < 4; ++ni) {                           \
    accv[0][ni] = __builtin_amdgcn_mfma_f32_16x16x32_bf16(                     \
        hf[0][kk], buf[ni], accv[0][ni], 0, 0, 0);                             \
    accv[1][ni] = __builtin_amdgcn_mfma_f32_16x16x32_bf16(                     \
        hf[1][kk], buf[ni], accv[1][ni], 0, 0, 0);                             \
  }
#define GEMM_TILE(accv, vp)                                                    \
  {                                                                            \
    bf16x8 va[4], vbu[4];                                                      \
    _Pragma("unroll") for (int ni = 0; ni < 4; ++ni) va[ni] = VLD(vp, ni, 0);  \
    _Pragma("unroll") for (int ni = 0; ni < 4; ++ni) vbu[ni] = VLD(vp, ni, 1); \
    MF(accv, va, 0)                                                            \
    _Pragma("unroll") for (int ni = 0; ni < 4; ++ni) va[ni] = VLD(vp, ni, 2);  \
    MF(accv, vbu, 1)                                                           \
    _Pragma("unroll") for (int ni = 0; ni < 4; ++ni) vbu[ni] = VLD(vp, ni, 3); \
    MF(accv, va, 2)                                                            \
    MF(accv, vbu, 3)                                                           \
  }

  float s[8];
#pragma unroll
  for (int r = 0; r < 8; ++r) s[r] = 0.f;

  // ---- pass 1: sum of exp(logit - 8) ----
  for (int c = 0; c < 8; ++c) {
    int colbase = c * 1024 + w * 64;
    if (colbase >= V_N) continue;
    const u16* vp = V2 + (size_t)(colbase >> 4) * 2048 + l * 8;
    f32x4 acc[2][4];
#pragma unroll
    for (int mi = 0; mi < 2; ++mi)
#pragma unroll
      for (int ni = 0; ni < 4; ++ni) acc[mi][ni] = (f32x4)0.f;
    GEMM_TILE(acc, vp)
    float vb[4];
#pragma unroll
    for (int ni = 0; ni < 4; ++ni) vb[ni] = Vb[colbase + ni * 16 + lr];
#pragma unroll
    for (int r = 0; r < 8; ++r) {
      int mi = r >> 2, j = r & 3;
      float e = 0.f;
#pragma unroll
      for (int ni = 0; ni < 4; ++ni)
        e += __expf(acc[mi][ni][j] + vb[ni] - 8.f);
      s[r] += e;
    }
  }
#pragma unroll
  for (int off = 1; off < 16; off <<= 1)
#pragma unroll
    for (int r = 0; r < 8; ++r) s[r] += __shfl_xor(s[r], off, 64);

  if (lr == 0) {
#pragma unroll
    for (int r = 0; r < 8; ++r)
      red[w][(r >> 2) * 16 + hq * 4 + (r & 3)] = s[r];
  }
  __syncthreads();
  if (t < 32) {
    float S = 0.f;
#pragma unroll
    for (int ww = 0; ww < 16; ++ww) S += red[ww][t];
    lse_s[t] = 8.f + __logf(S);
  }
  __syncthreads();
  float lse_r[8];
#pragma unroll
  for (int r = 0; r < 8; ++r)
    lse_r[r] = lse_s[(r >> 2) * 16 + hq * 4 + (r & 3)];

  // ---- pass 2: recompute, subtract, store ----
  for (int c = 0; c < 8; ++c) {
    int colbase = c * 1024 + w * 64;
    if (colbase >= V_N) continue;
    const u16* vp = V2 + (size_t)(colbase >> 4) * 2048 + l * 8;
    f32x4 acc[2][4];
#pragma unroll
    for (int mi = 0; mi < 2; ++mi)
#pragma unroll
      for (int ni = 0; ni < 4; ++ni) acc[mi][ni] = (f32x4)0.f;
    GEMM_TILE(acc, vp)
    float vb[4];
#pragma unroll
    for (int ni = 0; ni < 4; ++ni) vb[ni] = Vb[colbase + ni * 16 + lr];
#pragma unroll
    for (int mi = 0; mi < 2; ++mi)
#pragma unroll
      for (int j = 0; j < 4; ++j) {
        size_t gr = (size_t)(rowbase + mi * 16 + hq * 4 + j);
#pragma unroll
        for (int ni = 0; ni < 4; ++ni)
          out[gr * V_N + colbase + ni * 16 + lr] =
              acc[mi][ni][j] + vb[ni] - lse_r[mi * 4 + j];
      }
  }
#undef GEMM_TILE
#undef MF
#undef VLD
}

extern "C" void kernel_launch(void* const* d_in, const int* in_sizes, int n_in,
                              void* d_out, int out_size, void* d_ws,
                              size_t ws_size, hipStream_t stream) {
  const float* x      = (const float*)d_in[0];
  const float* hidden = (const float*)d_in[1];
  const float* c_in   = (const float*)d_in[2];
  const float* Ui = (const float*)d_in[3];
  const float* Uf = (const float*)d_in[4];
  const float* Uo = (const float*)d_in[5];
  const float* Ug = (const float*)d_in[6];
  const float* Wi = (const float*)d_in[7];
  const float* Wf = (const float*)d_in[8];
  const float* Wo = (const float*)d_in[9];
  const float* Wg = (const float*)d_in[10];
  const float* Vw = (const float*)d_in[11];
  const float* Uib = (const float*)d_in[12];
  const float* Ufb = (const float*)d_in[13];
  const float* Uob = (const float*)d_in[14];
  const float* Ugb = (const float*)d_in[15];
  const float* Wib = (const float*)d_in[16];
  const float* Wfb = (const float*)d_in[17];
  const float* Wob = (const float*)d_in[18];
  const float* Wgb = (const float*)d_in[19];
  const float* Vb  = (const float*)d_in[20];

  float* out   = (float*)d_out;
  float* h_out = out + (size_t)B_N * V_N;
  float* c_out = h_out + (size_t)B_N * H_N;

  char* ws = (char*)d_ws;
  float* tailf = (float*)ws;  ws += (size_t)B_N * TW * 4;        // 6.3 MB
  u16* Wc = (u16*)ws;         ws += (size_t)NKT * 2048 * 16;     // 8.4 MB
  u16* V2 = (u16*)ws;         ws += (size_t)500 * 256 * 16;      // 2.0 MB
  u16* gates_p = (u16*)ws;    ws += (size_t)4 * B_N * NG * 2;    // 33.6 MB

  pack_tail_kernel<<<dim3(768), dim3(256), 0, stream>>>(hidden, tailf);
  pack_w_kernel<<<dim3(2048), dim3(256), 0, stream>>>(Ui, Uf, Uo, Ug,
                                                      Wi, Wf, Wo, Wg, Wc);
  pack_vw_kernel<<<dim3(500), dim3(256), 0, stream>>>(Vw, V2);

  gates_gemm_kernel<<<dim3(512), dim3(512), 0, stream>>>(
      x, tailf, Wc, gates_p);

  logits_lsm_kernel<<<dim3(256), dim3(1024), 0, stream>>>(
      gates_p, c_in, Uib, Ufb, Uob, Ugb, Wib, Wfb, Wob, Wgb,
      V2, Vb, h_out, c_out, out);
}

// Round 11
// 221.350 us; speedup vs baseline: 1.1190x; 1.0002x over previous
//
#include <hip/hip_runtime.h>
#include <hip/hip_bf16.h>

typedef unsigned short u16;
typedef __attribute__((ext_vector_type(4))) float f32x4;
typedef __attribute__((ext_vector_type(16))) float f32x16;
typedef __attribute__((ext_vector_type(8))) short bf16x8;
typedef __attribute__((ext_vector_type(4))) short short4v;

#define B_N 8192
#define D_N 8000
#define H_N 100
#define V_N 8000
#define NG  512    // padded 4H
#define NKT 256    // K-steps of 32: 8192 total K (8000 x + 100 hidden + 92 pad)
#define TW  192    // tail width (hidden 100 + 92 zeros)

typedef const __attribute__((address_space(1))) unsigned int* gp_t;
typedef __attribute__((address_space(3))) unsigned int* lp_t;

static __device__ __forceinline__ short f2bf(float f) {
  unsigned u;
  __builtin_memcpy(&u, &f, 4);
  u = (u + 0x7fffu + ((u >> 16) & 1u)) >> 16;   // RNE
  return (short)u;
}
static __device__ __forceinline__ float bf2f(u16 b) {
  unsigned u = ((unsigned)b) << 16;
  float f;
  __builtin_memcpy(&f, &u, 4);
  return f;
}

// ---------------- pack hidden -> tail f32 [B_N][TW] (hidden | zeros) --------
__global__ __launch_bounds__(256) void pack_tail_kernel(
    const float* __restrict__ hidden, float* __restrict__ tail) {
  int idx = blockIdx.x * 256 + threadIdx.x;       // over B_N*24 chunks of 8
  if (idx >= B_N * 24) return;
  int b = idx / 24, c8 = (idx - b * 24) * 8;
  float o[8];
  if (c8 + 8 <= H_N) {
    const float* ph = hidden + (size_t)b * H_N + c8;
#pragma unroll
    for (int j = 0; j < 8; ++j) o[j] = ph[j];
  } else {
#pragma unroll
    for (int j = 0; j < 8; ++j) {
      int c = c8 + j;
      o[j] = (c < H_N) ? hidden[(size_t)b * H_N + c] : 0.f;
    }
  }
  f32x4 v0, v1;
#pragma unroll
  for (int j = 0; j < 4; ++j) { v0[j] = o[j]; v1[j] = o[4 + j]; }
  *(f32x4*)(tail + (size_t)b * TW + c8) = v0;
  *(f32x4*)(tail + (size_t)b * TW + c8 + 4) = v1;
}

// ---------------- pack U|W -> Wc, gld-linear physical order -----------------
__global__ __launch_bounds__(256) void pack_w_kernel(
    const float* __restrict__ U0, const float* __restrict__ U1,
    const float* __restrict__ U2, const float* __restrict__ U3,
    const float* __restrict__ W0, const float* __restrict__ W1,
    const float* __restrict__ W2, const float* __restrict__ W3,
    u16* __restrict__ Wc) {
  int idx = blockIdx.x * 256 + threadIdx.x;
  if (idx >= NKT * 2048) return;
  int t = idx >> 11;
  int j = idx & 2047;
  int pair = j >> 3, p = j & 7;
  int pl = p ^ (pair & 7);
  int n = pair * 2 + (pl >> 2);
  int s = pl & 3;
  int k0 = t * 32 + s * 8;
  bf16x8 ov;
  if (n >= 400) {
#pragma unroll
    for (int e = 0; e < 8; ++e) ov[e] = 0;
  } else {
    int g = n / 100;
    int r = n - g * 100;
    const float* U = (g == 0) ? U0 : (g == 1) ? U1 : (g == 2) ? U2 : U3;
    const float* W = (g == 0) ? W0 : (g == 1) ? W1 : (g == 2) ? W2 : W3;
    if (k0 + 8 <= D_N) {
      const float* pu = U + (size_t)r * D_N + k0;
      f32x4 v0 = *(const f32x4*)pu;
      f32x4 v1 = *(const f32x4*)(pu + 4);
#pragma unroll
      for (int e = 0; e < 4; ++e) { ov[e] = f2bf(v0[e]); ov[4 + e] = f2bf(v1[e]); }
    } else {
#pragma unroll
      for (int e = 0; e < 8; ++e) {
        int col = k0 + e - D_N;
        ov[e] = (col >= 0 && col < H_N) ? f2bf(W[(size_t)r * H_N + col]) : (short)0;
      }
    }
  }
  *(bf16x8*)(Wc + (size_t)idx * 8) = ov;
}

// ---------------- pack V_w -> V2, MFMA-native layout ------------------------
__global__ __launch_bounds__(256) void pack_vw_kernel(
    const float* __restrict__ Vw, u16* __restrict__ V2) {
  int idx = blockIdx.x * 256 + threadIdx.x;
  if (idx >= 500 * 256) return;
  int n16 = idx >> 8, r = idx & 255;
  int kk = r >> 6, q = r & 63;
  int h = q >> 4, lr = q & 15;
  int n = n16 * 16 + lr;
  int k0 = kk * 32 + h * 8;
  bf16x8 ov;
#pragma unroll
  for (int e = 0; e < 8; ++e) {
    int col = k0 + e;
    ov[e] = (col < H_N) ? f2bf(Vw[(size_t)n * H_N + col]) : (short)0;
  }
  *(bf16x8*)(V2 + (size_t)idx * 8) = ov;
}

// ---------------- gates GEMM: BM=64, BN=512, BK=32, splitK=4 ----------------
// R7 schedule + RACE FIX: sched_barrier(0) between the GLD_B cluster and the
// A-register load pins issue order so the vmcnt(6) accounting is exact.
// (Without the pin, LLVM may hoist the A-load above global_load_lds — they
// don't alias — leaving one B-load of the CURRENT tile unretired at COMPUTE:
// a timing-marginal race matching the intermittent R8-R10 failures.)
__global__ __launch_bounds__(512, 4) void gates_gemm_kernel(
    const float* __restrict__ x, const float* __restrict__ tail,
    const u16* __restrict__ Wc, u16* __restrict__ Cp) {
  __shared__ __align__(16) u16 As[2][2048];     // 4 KB each, pair-XOR swizzled
  __shared__ __align__(16) u16 Bs[2][16384];    // 32 KB each, pre-swizzled src
  const int t = threadIdx.x;
  const int w = t >> 6, l = t & 63;
  const int bid = blockIdx.x;
  const int xcd = bid & 7;
  const int kz = xcd >> 1;
  const int bm = (bid >> 3) | ((xcd & 1) << 6);   // 0..127, bijective with kz
  const int t0 = kz * 64;
  const int tmax = t0 + 63;

  const int arow = t >> 3, ao = t & 7;
  const float* xrow = x + (size_t)(bm * 64 + arow) * D_N + ao * 4;
  const float* trow = tail + (size_t)(bm * 64 + arow) * TW + ao * 4;
  const int apair = arow >> 1;
  const int awr = apair * 64 + ((((arow & 1) << 2) | (ao >> 1)) ^ (apair & 7)) * 8
                  + (ao & 1) * 4;  // u16 units

  const int wn = w * 64;
  int aoff[2][2], boff[2][2];
#pragma unroll
  for (int kk = 0; kk < 2; ++kk)
#pragma unroll
    for (int i = 0; i < 2; ++i) {
      int rowa = i * 32 + (l & 31);
      int sa = kk * 2 + (l >> 5);
      int pa = rowa >> 1;
      aoff[kk][i] = pa * 64 + ((((rowa & 1) << 2) | sa) ^ (pa & 7)) * 8;
      int rowb = wn + i * 32 + (l & 31);
      int pb = rowb >> 1;
      boff[kk][i] = pb * 64 + ((((rowb & 1) << 2) | sa) ^ (pb & 7)) * 8;
    }

  f32x16 acc00 = (f32x16)0.f, acc01 = (f32x16)0.f;
  f32x16 acc10 = (f32x16)0.f, acc11 = (f32x16)0.f;

#define ASRC(tt) ((tt) < 250 ? xrow + (size_t)(tt) * 32 : trow + (size_t)((tt) - 250) * 32)
#define GLD_B(tt, buf)                                                         \
  _Pragma("unroll") for (int q = 0; q < 4; ++q)                                \
      __builtin_amdgcn_global_load_lds(                                        \
          (gp_t)(const void*)(Wc + ((size_t)(tt) * 2048 + t + q * 512) * 8),   \
          (lp_t)(void*)((u16*)Bs[buf] + (t + q * 512) * 8), 16, 0, 0);
#define DSW_A(buf, rv)                                                         \
  {                                                                            \
    short4v wv;                                                                \
    wv[0] = f2bf(rv[0]); wv[1] = f2bf(rv[1]);                                  \
    wv[2] = f2bf(rv[2]); wv[3] = f2bf(rv[3]);                                  \
    *(short4v*)((u16*)As[buf] + awr) = wv;                                     \
  }
#define COMPUTE(buf)                                                           \
  _Pragma("unroll") for (int kk = 0; kk < 2; ++kk) {                           \
    bf16x8 af0 = *(const bf16x8*)((const u16*)As[buf] + aoff[kk][0]);          \
    bf16x8 af1 = *(const bf16x8*)((const u16*)As[buf] + aoff[kk][1]);          \
    bf16x8 bv0 = *(const bf16x8*)((const u16*)Bs[buf] + boff[kk][0]);          \
    bf16x8 bv1 = *(const bf16x8*)((const u16*)Bs[buf] + boff[kk][1]);          \
    acc00 = __builtin_amdgcn_mfma_f32_32x32x16_bf16(af0, bv0, acc00, 0, 0, 0); \
    acc01 = __builtin_amdgcn_mfma_f32_32x32x16_bf16(af0, bv1, acc01, 0, 0, 0); \
    acc10 = __builtin_amdgcn_mfma_f32_32x32x16_bf16(af1, bv0, acc10, 0, 0, 0); \
    acc11 = __builtin_amdgcn_mfma_f32_32x32x16_bf16(af1, bv1, acc11, 0, 0, 0); \
  }
// body tc: barrier | GLD_B(tc+1) | <pin> | A-load(tc+4) | <pin> | vmcnt(6)
// (retires B(tc)x4 + two oldest A) | DSW(A(tc+1)) | lgkm | barrier | COMPUTE(tc)
#define BODY(CB, SUSE, SDEF, tc)                                               \
  {                                                                            \
    __builtin_amdgcn_s_barrier();                                              \
    int tb = (tc) + 1 > tmax ? tmax : (tc) + 1;                                \
    GLD_B(tb, (CB) ^ 1);                                                       \
    __builtin_amdgcn_sched_barrier(0); /* RACE FIX: pin GLD_B before A-load */ \
    int ta = (tc) + 4 > tmax ? tmax : (tc) + 4;                                \
    SDEF = *(const f32x4*)ASRC(ta);                                            \
    __builtin_amdgcn_sched_barrier(0);                                         \
    asm volatile("s_waitcnt vmcnt(6)" ::: "memory");                           \
    __builtin_amdgcn_sched_barrier(0);                                         \
    DSW_A((CB) ^ 1, SUSE);                                                     \
    asm volatile("s_waitcnt lgkmcnt(0)" ::: "memory");                         \
    __builtin_amdgcn_s_barrier();                                              \
    __builtin_amdgcn_sched_barrier(0);                                         \
    COMPUTE(CB);                                                               \
  }

  f32x4 s0, s1, s2, s3;
  {
    f32x4 r0 = *(const f32x4*)ASRC(t0);
    asm volatile("s_waitcnt vmcnt(0)" ::: "memory");
    DSW_A(0, r0);
  }
  GLD_B(t0, 0);
  __builtin_amdgcn_sched_barrier(0);
  s0 = *(const f32x4*)ASRC(t0 + 1);
  s1 = *(const f32x4*)ASRC(t0 + 2);
  s2 = *(const f32x4*)ASRC(t0 + 3);
  __builtin_amdgcn_sched_barrier(0);

  for (int tt = t0; tt < t0 + 64; tt += 4) {
    BODY(0, s0, s3, tt);
    BODY(1, s1, s0, tt + 1);
    BODY(0, s2, s1, tt + 2);
    BODY(1, s3, s2, tt + 3);
  }

  // epilogue: store acc to bf16 partial buffer kz
  u16* Cg = Cp + (size_t)kz * B_N * NG;
  const int lcol = l & 31, lhi = (l >> 5) * 4;
#pragma unroll
  for (int mi = 0; mi < 2; ++mi)
#pragma unroll
    for (int ni = 0; ni < 2; ++ni) {
      f32x16 a = (mi == 0) ? (ni == 0 ? acc00 : acc01)
                           : (ni == 0 ? acc10 : acc11);
#pragma unroll
      for (int reg = 0; reg < 16; ++reg) {
        int row = bm * 64 + mi * 32 + (reg & 3) + 8 * (reg >> 2) + lhi;
        Cg[(size_t)row * NG + wn + ni * 32 + lcol] = (u16)f2bf(a[reg]);
      }
    }
#undef BODY
#undef COMPUTE
#undef DSW_A
#undef GLD_B
#undef ASRC
}

// ---------------- fused act + logits + log_softmax (exact R7 version) -------
__global__ __launch_bounds__(1024, 4) void logits_lsm_kernel(
    const u16* __restrict__ gp, const float* __restrict__ c_in,
    const float* __restrict__ biu, const float* __restrict__ bfu,
    const float* __restrict__ bou, const float* __restrict__ bgu,
    const float* __restrict__ biw, const float* __restrict__ bfw,
    const float* __restrict__ bow, const float* __restrict__ bgw,
    const u16* __restrict__ V2, const float* __restrict__ Vb,
    float* __restrict__ h_out, float* __restrict__ c_out,
    float* __restrict__ out) {
  __shared__ u16 hs[32][128];
  __shared__ float red[16][32];
  __shared__ float lse_s[32];
  int t = threadIdx.x, w = t >> 6, l = t & 63;
  int lr = l & 15, hq = l >> 4;
  int rowbase = blockIdx.x * 32;

  // ---- phase 0: LSTM pointwise for our 32 rows ----
  if (t < 32 * 28) hs[t / 28][100 + t % 28] = 0;
  const size_t st = (size_t)B_N * NG;
  for (int i = t; i < 3200; i += 1024) {
    int b = i / 100, r = i - b * 100;
    int row = rowbase + b;
    const u16* g0 = gp + (size_t)row * NG;
    float gi = bf2f(g0[r]) + bf2f(g0[r + st]) + bf2f(g0[r + 2 * st]) +
               bf2f(g0[r + 3 * st]) + biu[r] + biw[r];
    float gf = bf2f(g0[r + 100]) + bf2f(g0[r + 100 + st]) +
               bf2f(g0[r + 100 + 2 * st]) + bf2f(g0[r + 100 + 3 * st]) +
               bfu[r] + bfw[r];
    float go = bf2f(g0[r + 200]) + bf2f(g0[r + 200 + st]) +
               bf2f(g0[r + 200 + 2 * st]) + bf2f(g0[r + 200 + 3 * st]) +
               bou[r] + bow[r];
    float gg = bf2f(g0[r + 300]) + bf2f(g0[r + 300 + st]) +
               bf2f(g0[r + 300 + 2 * st]) + bf2f(g0[r + 300 + 3 * st]) +
               bgu[r] + bgw[r];
    float it = 1.f / (1.f + __expf(-gi));
    float ft = 1.f / (1.f + __expf(-gf));
    float ot = 1.f / (1.f + __expf(-go));
    float gt = tanhf(gg);
    float ct = c_in[(size_t)row * H_N + r] * ft + gt * it;
    float ht = tanhf(ct) * ot;
    h_out[(size_t)row * H_N + r] = ht;
    c_out[(size_t)row * H_N + r] = ct;
    hs[b][r] = (u16)f2bf(ht);
  }
  __syncthreads();

  bf16x8 hf[2][4];
#pragma unroll
  for (int mi = 0; mi < 2; ++mi)
#pragma unroll
    for (int kk = 0; kk < 4; ++kk)
      hf[mi][kk] = *(const bf16x8*)(&hs[mi * 16 + lr][kk * 32 + hq * 8]);

// vp points at this wave's 64-col group; frag (ni,kk) at vp + (ni*4+kk)*512
#define VLD(vp, ni, kk) (*(const bf16x8*)((vp) + ((ni) * 4 + (kk)) * 512))
#define MF(accv, buf, kk)                                                      \
  _Pragma("unroll") for (int ni = 0; ni < 4; ++ni) {                           \
    accv[0][ni] = __builtin_amdgcn_mfma_f32_16x16x32_bf16(                     \
        hf[0][kk], buf[ni], accv[0][ni], 0, 0, 0);                             \
    accv[1][ni] = __builtin_amdgcn_mfma_f32_16x16x32_bf16(                     \
        hf[1][kk], buf[ni], accv[1][ni], 0, 0, 0);                             \
  }
#define GEMM_TILE(accv, vp)                                                    \
  {                                                                            \
    bf16x8 va[4], vbu[4];                                                      \
    _Pragma("unroll") for (int ni = 0; ni < 4; ++ni) va[ni] = VLD(vp, ni, 0);  \
    _Pragma("unroll") for (int ni = 0; ni < 4; ++ni) vbu[ni] = VLD(vp, ni, 1); \
    MF(accv, va, 0)                                                            \
    _Pragma("unroll") for (int ni = 0; ni < 4; ++ni) va[ni] = VLD(vp, ni, 2);  \
    MF(accv, vbu, 1)                                                           \
    _Pragma("unroll") for (int ni = 0; ni < 4; ++ni) vbu[ni] = VLD(vp, ni, 3); \
    MF(accv, va, 2)                                                            \
    MF(accv, vbu, 3)                                                           \
  }

  float s[8];
#pragma unroll
  for (int r = 0; r < 8; ++r) s[r] = 0.f;

  // ---- pass 1: sum of exp(logit - 8) ----
  for (int c = 0; c < 8; ++c) {
    int colbase = c * 1024 + w * 64;
    if (colbase >= V_N) continue;
    const u16* vp = V2 + (size_t)(colbase >> 4) * 2048 + l * 8;
    f32x4 acc[2][4];
#pragma unroll
    for (int mi = 0; mi < 2; ++mi)
#pragma unroll
      for (int ni = 0; ni < 4; ++ni) acc[mi][ni] = (f32x4)0.f;
    GEMM_TILE(acc, vp)
    float vb[4];
#pragma unroll
    for (int ni = 0; ni < 4; ++ni) vb[ni] = Vb[colbase + ni * 16 + lr];
#pragma unroll
    for (int r = 0; r < 8; ++r) {
      int mi = r >> 2, j = r & 3;
      float e = 0.f;
#pragma unroll
      for (int ni = 0; ni < 4; ++ni)
        e += __expf(acc[mi][ni][j] + vb[ni] - 8.f);
      s[r] += e;
    }
  }
#pragma unroll
  for (int off = 1; off < 16; off <<= 1)
#pragma unroll
    for (int r = 0; r < 8; ++r) s[r] += __shfl_xor(s[r], off, 64);

  if (lr == 0) {
#pragma unroll
    for (int r = 0; r < 8; ++r)
      red[w][(r >> 2) * 16 + hq * 4 + (r & 3)] = s[r];
  }
  __syncthreads();
  if (t < 32) {
    float S = 0.f;
#pragma unroll
    for (int ww = 0; ww < 16; ++ww) S += red[ww][t];
    lse_s[t] = 8.f + __logf(S);
  }
  __syncthreads();
  float lse_r[8];
#pragma unroll
  for (int r = 0; r < 8; ++r)
    lse_r[r] = lse_s[(r >> 2) * 16 + hq * 4 + (r & 3)];

  // ---- pass 2: recompute, subtract, store ----
  for (int c = 0; c < 8; ++c) {
    int colbase = c * 1024 + w * 64;
    if (colbase >= V_N) continue;
    const u16* vp = V2 + (size_t)(colbase >> 4) * 2048 + l * 8;
    f32x4 acc[2][4];
#pragma unroll
    for (int mi = 0; mi < 2; ++mi)
#pragma unroll
      for (int ni = 0; ni < 4; ++ni) acc[mi][ni] = (f32x4)0.f;
    GEMM_TILE(acc, vp)
    float vb[4];
#pragma unroll
    for (int ni = 0; ni < 4; ++ni) vb[ni] = Vb[colbase + ni * 16 + lr];
#pragma unroll
    for (int mi = 0; mi < 2; ++mi)
#pragma unroll
      for (int j = 0; j < 4; ++j) {
        size_t gr = (size_t)(rowbase + mi * 16 + hq * 4 + j);
#pragma unroll
        for (int ni = 0; ni < 4; ++ni)
          out[gr * V_N + colbase + ni * 16 + lr] =
              acc[mi][ni][j] + vb[ni] - lse_r[mi * 4 + j];
      }
  }
#undef GEMM_TILE
#undef MF
#undef VLD
}

extern "C" void kernel_launch(void* const* d_in, const int* in_sizes, int n_in,
                              void* d_out, int out_size, void* d_ws,
                              size_t ws_size, hipStream_t stream) {
  const float* x      = (const float*)d_in[0];
  const float* hidden = (const float*)d_in[1];
  const float* c_in   = (const float*)d_in[2];
  const float* Ui = (const float*)d_in[3];
  const float* Uf = (const float*)d_in[4];
  const float* Uo = (const float*)d_in[5];
  const float* Ug = (const float*)d_in[6];
  const float* Wi = (const float*)d_in[7];
  const float* Wf = (const float*)d_in[8];
  const float* Wo = (const float*)d_in[9];
  const float* Wg = (const float*)d_in[10];
  const float* Vw = (const float*)d_in[11];
  const float* Uib = (const float*)d_in[12];
  const float* Ufb = (const float*)d_in[13];
  const float* Uob = (const float*)d_in[14];
  const float* Ugb = (const float*)d_in[15];
  const float* Wib = (const float*)d_in[16];
  const float* Wfb = (const float*)d_in[17];
  const float* Wob = (const float*)d_in[18];
  const float* Wgb = (const float*)d_in[19];
  const float* Vb  = (const float*)d_in[20];

  float* out   = (float*)d_out;
  float* h_out = out + (size_t)B_N * V_N;
  float* c_out = h_out + (size_t)B_N * H_N;

  char* ws = (char*)d_ws;
  float* tailf = (float*)ws;  ws += (size_t)B_N * TW * 4;        // 6.3 MB
  u16* Wc = (u16*)ws;         ws += (size_t)NKT * 2048 * 16;     // 8.4 MB
  u16* V2 = (u16*)ws;         ws += (size_t)500 * 256 * 16;      // 2.0 MB
  u16* gates_p = (u16*)ws;    ws += (size_t)4 * B_N * NG * 2;    // 33.6 MB

  pack_tail_kernel<<<dim3(768), dim3(256), 0, stream>>>(hidden, tailf);
  pack_w_kernel<<<dim3(2048), dim3(256), 0, stream>>>(Ui, Uf, Uo, Ug,
                                                      Wi, Wf, Wo, Wg, Wc);
  pack_vw_kernel<<<dim3(500), dim3(256), 0, stream>>>(Vw, V2);

  gates_gemm_kernel<<<dim3(512), dim3(512), 0, stream>>>(
      x, tailf, Wc, gates_p);

  logits_lsm_kernel<<<dim3(256), dim3(1024), 0, stream>>>(
      gates_p, c_in, Uib, Ufb, Uob, Ugb, Wib, Wfb, Wob, Wgb,
      V2, Vb, h_out, c_out, out);
}

// Round 13
// 215.313 us; speedup vs baseline: 1.1504x; 1.0280x over previous
//
#include <hip/hip_runtime.h>
#include <hip/hip_bf16.h>

typedef unsigned short u16;
typedef __attribute__((ext_vector_type(4))) float f32x4;
typedef __attribute__((ext_vector_type(16))) float f32x16;
typedef __attribute__((ext_vector_type(8))) short bf16x8;
typedef __attribute__((ext_vector_type(4))) short short4v;

#define B_N 8192
#define D_N 8000
#define H_N 100
#define V_N 8000
#define NG  512    // padded 4H
#define NKT 256    // K-steps of 32: 8192 total K (8000 x + 100 hidden + 92 pad)
#define TW  192    // tail width (hidden 100 + 92 zeros)

typedef const __attribute__((address_space(1))) unsigned int* gp_t;
typedef __attribute__((address_space(3))) unsigned int* lp_t;

static __device__ __forceinline__ short f2bf(float f) {
  unsigned u;
  __builtin_memcpy(&u, &f, 4);
  u = (u + 0x7fffu + ((u >> 16) & 1u)) >> 16;   // RNE
  return (short)u;
}
static __device__ __forceinline__ float bf2f(u16 b) {
  unsigned u = ((unsigned)b) << 16;
  float f;
  __builtin_memcpy(&f, &u, 4);
  return f;
}

// ---------------- pack hidden -> tail f32 [B_N][TW] (hidden | zeros) --------
__global__ __launch_bounds__(256) void pack_tail_kernel(
    const float* __restrict__ hidden, float* __restrict__ tail) {
  int idx = blockIdx.x * 256 + threadIdx.x;       // over B_N*24 chunks of 8
  if (idx >= B_N * 24) return;
  int b = idx / 24, c8 = (idx - b * 24) * 8;
  float o[8];
  if (c8 + 8 <= H_N) {
    const float* ph = hidden + (size_t)b * H_N + c8;
#pragma unroll
    for (int j = 0; j < 8; ++j) o[j] = ph[j];
  } else {
#pragma unroll
    for (int j = 0; j < 8; ++j) {
      int c = c8 + j;
      o[j] = (c < H_N) ? hidden[(size_t)b * H_N + c] : 0.f;
    }
  }
  f32x4 v0, v1;
#pragma unroll
  for (int j = 0; j < 4; ++j) { v0[j] = o[j]; v1[j] = o[4 + j]; }
  *(f32x4*)(tail + (size_t)b * TW + c8) = v0;
  *(f32x4*)(tail + (size_t)b * TW + c8 + 4) = v1;
}

// ---------------- pack U|W -> Wc, gld-linear physical order -----------------
__global__ __launch_bounds__(256) void pack_w_kernel(
    const float* __restrict__ U0, const float* __restrict__ U1,
    const float* __restrict__ U2, const float* __restrict__ U3,
    const float* __restrict__ W0, const float* __restrict__ W1,
    const float* __restrict__ W2, const float* __restrict__ W3,
    u16* __restrict__ Wc) {
  int idx = blockIdx.x * 256 + threadIdx.x;
  if (idx >= NKT * 2048) return;
  int t = idx >> 11;
  int j = idx & 2047;
  int pair = j >> 3, p = j & 7;
  int pl = p ^ (pair & 7);
  int n = pair * 2 + (pl >> 2);
  int s = pl & 3;
  int k0 = t * 32 + s * 8;
  bf16x8 ov;
  if (n >= 400) {
#pragma unroll
    for (int e = 0; e < 8; ++e) ov[e] = 0;
  } else {
    int g = n / 100;
    int r = n - g * 100;
    const float* U = (g == 0) ? U0 : (g == 1) ? U1 : (g == 2) ? U2 : U3;
    const float* W = (g == 0) ? W0 : (g == 1) ? W1 : (g == 2) ? W2 : W3;
    if (k0 + 8 <= D_N) {
      const float* pu = U + (size_t)r * D_N + k0;
      f32x4 v0 = *(const f32x4*)pu;
      f32x4 v1 = *(const f32x4*)(pu + 4);
#pragma unroll
      for (int e = 0; e < 4; ++e) { ov[e] = f2bf(v0[e]); ov[4 + e] = f2bf(v1[e]); }
    } else {
#pragma unroll
      for (int e = 0; e < 8; ++e) {
        int col = k0 + e - D_N;
        ov[e] = (col >= 0 && col < H_N) ? f2bf(W[(size_t)r * H_N + col]) : (short)0;
      }
    }
  }
  *(bf16x8*)(Wc + (size_t)idx * 8) = ov;
}

// ---------------- pack V_w -> V2, MFMA-native layout ------------------------
__global__ __launch_bounds__(256) void pack_vw_kernel(
    const float* __restrict__ Vw, u16* __restrict__ V2) {
  int idx = blockIdx.x * 256 + threadIdx.x;
  if (idx >= 500 * 256) return;
  int n16 = idx >> 8, r = idx & 255;
  int kk = r >> 6, q = r & 63;
  int h = q >> 4, lr = q & 15;
  int n = n16 * 16 + lr;
  int k0 = kk * 32 + h * 8;
  bf16x8 ov;
#pragma unroll
  for (int e = 0; e < 8; ++e) {
    int col = k0 + e;
    ov[e] = (col < H_N) ? f2bf(Vw[(size_t)n * H_N + col]) : (short)0;
  }
  *(bf16x8*)(V2 + (size_t)idx * 8) = ov;
}

// ---------------- gates GEMM: BM=64, BN=512, BK=32, splitK=4 ----------------
// DRAIN-ONLY schedule (no counted vmcnt anywhere — race-free by construction):
// per K-step: issue GLD_B(k+1)+A-load(k+1), COMPUTE(k) overlapping the loads,
// then s_waitcnt vmcnt(0) (full drain, correct regardless of compiler spills
// or extra VMEM), DSW_A, lgkmcnt(0), one s_barrier. 2 blocks/CU TLP covers the
// residual drain stall. XCD-aware kz decode keeps Wc per-XCD L2 resident.
__global__ __launch_bounds__(512, 4) void gates_gemm_kernel(
    const float* __restrict__ x, const float* __restrict__ tail,
    const u16* __restrict__ Wc, u16* __restrict__ Cp) {
  __shared__ __align__(16) u16 As[2][2048];     // 4 KB each, pair-XOR swizzled
  __shared__ __align__(16) u16 Bs[2][16384];    // 32 KB each, pre-swizzled src
  const int t = threadIdx.x;
  const int w = t >> 6, l = t & 63;
  const int bid = blockIdx.x;
  const int xcd = bid & 7;
  const int kz = xcd >> 1;
  const int bm = (bid >> 3) | ((xcd & 1) << 6);   // 0..127, bijective with kz
  const int t0 = kz * 64;
  const int tmax = t0 + 63;

  const int arow = t >> 3, ao = t & 7;
  const float* xrow = x + (size_t)(bm * 64 + arow) * D_N + ao * 4;
  const float* trow = tail + (size_t)(bm * 64 + arow) * TW + ao * 4;
  const int apair = arow >> 1;
  const int awr = apair * 64 + ((((arow & 1) << 2) | (ao >> 1)) ^ (apair & 7)) * 8
                  + (ao & 1) * 4;  // u16 units

  const int wn = w * 64;
  int aoff[2][2], boff[2][2];
#pragma unroll
  for (int kk = 0; kk < 2; ++kk)
#pragma unroll
    for (int i = 0; i < 2; ++i) {
      int rowa = i * 32 + (l & 31);
      int sa = kk * 2 + (l >> 5);
      int pa = rowa >> 1;
      aoff[kk][i] = pa * 64 + ((((rowa & 1) << 2) | sa) ^ (pa & 7)) * 8;
      int rowb = wn + i * 32 + (l & 31);
      int pb = rowb >> 1;
      boff[kk][i] = pb * 64 + ((((rowb & 1) << 2) | sa) ^ (pb & 7)) * 8;
    }

  f32x16 acc00 = (f32x16)0.f, acc01 = (f32x16)0.f;
  f32x16 acc10 = (f32x16)0.f, acc11 = (f32x16)0.f;

#define ASRC(tt) ((tt) < 250 ? xrow + (size_t)(tt) * 32 : trow + (size_t)((tt) - 250) * 32)
#define GLD_B(tt, buf)                                                         \
  _Pragma("unroll") for (int q = 0; q < 4; ++q)                                \
      __builtin_amdgcn_global_load_lds(                                        \
          (gp_t)(const void*)(Wc + ((size_t)(tt) * 2048 + t + q * 512) * 8),   \
          (lp_t)(void*)((u16*)Bs[buf] + (t + q * 512) * 8), 16, 0, 0);
#define DSW_A(buf, rv)                                                         \
  {                                                                            \
    short4v wv;                                                                \
    wv[0] = f2bf(rv[0]); wv[1] = f2bf(rv[1]);                                  \
    wv[2] = f2bf(rv[2]); wv[3] = f2bf(rv[3]);                                  \
    *(short4v*)((u16*)As[buf] + awr) = wv;                                     \
  }
#define COMPUTE(buf)                                                           \
  _Pragma("unroll") for (int kk = 0; kk < 2; ++kk) {                           \
    bf16x8 af0 = *(const bf16x8*)((const u16*)As[buf] + aoff[kk][0]);          \
    bf16x8 af1 = *(const bf16x8*)((const u16*)As[buf] + aoff[kk][1]);          \
    bf16x8 bv0 = *(const bf16x8*)((const u16*)Bs[buf] + boff[kk][0]);          \
    bf16x8 bv1 = *(const bf16x8*)((const u16*)Bs[buf] + boff[kk][1]);          \
    acc00 = __builtin_amdgcn_mfma_f32_32x32x16_bf16(af0, bv0, acc00, 0, 0, 0); \
    acc01 = __builtin_amdgcn_mfma_f32_32x32x16_bf16(af0, bv1, acc01, 0, 0, 0); \
    acc10 = __builtin_amdgcn_mfma_f32_32x32x16_bf16(af1, bv0, acc10, 0, 0, 0); \
    acc11 = __builtin_amdgcn_mfma_f32_32x32x16_bf16(af1, bv1, acc11, 0, 0, 0); \
  }
// body tc: [issue B(tc+1)->buf^1 and A(tc+1)->reg] | COMPUTE(tc) under the
// loads | vmcnt(0) full drain | DSW_A | lgkmcnt(0) | barrier. One barrier
// per step; every wait is a full drain -> no counting to get wrong.
#define BODY(CB, tc)                                                           \
  {                                                                            \
    int tn = (tc) + 1 > tmax ? tmax : (tc) + 1;                                \
    GLD_B(tn, (CB) ^ 1);                                                       \
    ra = *(const f32x4*)ASRC(tn);                                              \
    __builtin_amdgcn_sched_barrier(0);                                         \
    COMPUTE(CB);                                                               \
    __builtin_amdgcn_sched_barrier(0);                                         \
    asm volatile("s_waitcnt vmcnt(0)" ::: "memory");                           \
    __builtin_amdgcn_sched_barrier(0);                                         \
    DSW_A((CB) ^ 1, ra);                                                       \
    asm volatile("s_waitcnt lgkmcnt(0)" ::: "memory");                         \
    __builtin_amdgcn_s_barrier();                                              \
  }

  // Prologue: stage tile t0 into buf0, full drain, barrier.
  f32x4 ra;
  {
    f32x4 r0 = *(const f32x4*)ASRC(t0);
    GLD_B(t0, 0);
    asm volatile("s_waitcnt vmcnt(0)" ::: "memory");
    DSW_A(0, r0);
    asm volatile("s_waitcnt lgkmcnt(0)" ::: "memory");
    __builtin_amdgcn_s_barrier();
  }

  for (int tt = t0; tt < t0 + 64; tt += 2) {
    BODY(0, tt);
    BODY(1, tt + 1);
  }

  // epilogue: store acc to bf16 partial buffer kz
  u16* Cg = Cp + (size_t)kz * B_N * NG;
  const int lcol = l & 31, lhi = (l >> 5) * 4;
#pragma unroll
  for (int mi = 0; mi < 2; ++mi)
#pragma unroll
    for (int ni = 0; ni < 2; ++ni) {
      f32x16 a = (mi == 0) ? (ni == 0 ? acc00 : acc01)
                           : (ni == 0 ? acc10 : acc11);
#pragma unroll
      for (int reg = 0; reg < 16; ++reg) {
        int row = bm * 64 + mi * 32 + (reg & 3) + 8 * (reg >> 2) + lhi;
        Cg[(size_t)row * NG + wn + ni * 32 + lcol] = (u16)f2bf(a[reg]);
      }
    }
#undef BODY
#undef COMPUTE
#undef DSW_A
#undef GLD_B
#undef ASRC
}

// ---------------- fused act + logits + log_softmax (exact R11 version) ------
__global__ __launch_bounds__(1024, 4) void logits_lsm_kernel(
    const u16* __restrict__ gp, const float* __restrict__ c_in,
    const float* __restrict__ biu, const float* __restrict__ bfu,
    const float* __restrict__ bou, const float* __restrict__ bgu,
    const float* __restrict__ biw, const float* __restrict__ bfw,
    const float* __restrict__ bow, const float* __restrict__ bgw,
    const u16* __restrict__ V2, const float* __restrict__ Vb,
    float* __restrict__ h_out, float* __restrict__ c_out,
    float* __restrict__ out) {
  __shared__ u16 hs[32][128];
  __shared__ float red[16][32];
  __shared__ float lse_s[32];
  int t = threadIdx.x, w = t >> 6, l = t & 63;
  int lr = l & 15, hq = l >> 4;
  int rowbase = blockIdx.x * 32;

  // ---- phase 0: LSTM pointwise for our 32 rows ----
  if (t < 32 * 28) hs[t / 28][100 + t % 28] = 0;
  const size_t st = (size_t)B_N * NG;
  for (int i = t; i < 3200; i += 1024) {
    int b = i / 100, r = i - b * 100;
    int row = rowbase + b;
    const u16* g0 = gp + (size_t)row * NG;
    float gi = bf2f(g0[r]) + bf2f(g0[r + st]) + bf2f(g0[r + 2 * st]) +
               bf2f(g0[r + 3 * st]) + biu[r] + biw[r];
    float gf = bf2f(g0[r + 100]) + bf2f(g0[r + 100 + st]) +
               bf2f(g0[r + 100 + 2 * st]) + bf2f(g0[r + 100 + 3 * st]) +
               bfu[r] + bfw[r];
    float go = bf2f(g0[r + 200]) + bf2f(g0[r + 200 + st]) +
               bf2f(g0[r + 200 + 2 * st]) + bf2f(g0[r + 200 + 3 * st]) +
               bou[r] + bow[r];
    float gg = bf2f(g0[r + 300]) + bf2f(g0[r + 300 + st]) +
               bf2f(g0[r + 300 + 2 * st]) + bf2f(g0[r + 300 + 3 * st]) +
               bgu[r] + bgw[r];
    float it = 1.f / (1.f + __expf(-gi));
    float ft = 1.f / (1.f + __expf(-gf));
    float ot = 1.f / (1.f + __expf(-go));
    float gt = tanhf(gg);
    float ct = c_in[(size_t)row * H_N + r] * ft + gt * it;
    float ht = tanhf(ct) * ot;
    h_out[(size_t)row * H_N + r] = ht;
    c_out[(size_t)row * H_N + r] = ct;
    hs[b][r] = (u16)f2bf(ht);
  }
  __syncthreads();

  bf16x8 hf[2][4];
#pragma unroll
  for (int mi = 0; mi < 2; ++mi)
#pragma unroll
    for (int kk = 0; kk < 4; ++kk)
      hf[mi][kk] = *(const bf16x8*)(&hs[mi * 16 + lr][kk * 32 + hq * 8]);

// vp points at this wave's 64-col group; frag (ni,kk) at vp + (ni*4+kk)*512
#define VLD(vp, ni, kk) (*(const bf16x8*)((vp) + ((ni) * 4 + (kk)) * 512))
#define MF(accv, buf, kk)                                                      \
  _Pragma("unroll") for (int ni = 0; ni < 4; ++ni) {                           \
    accv[0][ni] = __builtin_amdgcn_mfma_f32_16x16x32_bf16(                     \
        hf[0][kk], buf[ni], accv[0][ni], 0, 0, 0);                             \
    accv[1][ni] = __builtin_amdgcn_mfma_f32_16x16x32_bf16(                     \
        hf[1][kk], buf[ni], accv[1][ni], 0, 0, 0);                             \
  }
#define GEMM_TILE(accv, vp)                                                    \
  {                                                                            \
    bf16x8 va[4], vbu[4];                                                      \
    _Pragma("unroll") for (int ni = 0; ni < 4; ++ni) va[ni] = VLD(vp, ni, 0);  \
    _Pragma("unroll") for (int ni = 0; ni < 4; ++ni) vbu[ni] = VLD(vp, ni, 1); \
    MF(accv, va, 0)                                                            \
    _Pragma("unroll") for (int ni = 0; ni < 4; ++ni) va[ni] = VLD(vp, ni, 2);  \
    MF(accv, vbu, 1)                                                           \
    _Pragma("unroll") for (int ni = 0; ni < 4; ++ni) vbu[ni] = VLD(vp, ni, 3); \
    MF(accv, va, 2)                                                            \
    MF(accv, vbu, 3)                                                           \
  }

  float s[8];
#pragma unroll
  for (int r = 0; r < 8; ++r) s[r] = 0.f;

  // ---- pass 1: sum of exp(logit - 8) ----
  for (int c = 0; c < 8; ++c) {
    int colbase = c * 1024 + w * 64;
    if (colbase >= V_N) continue;
    const u16* vp = V2 + (size_t)(colbase >> 4) * 2048 + l * 8;
    f32x4 acc[2][4];
#pragma unroll
    for (int mi = 0; mi < 2; ++mi)
#pragma unroll
      for (int ni = 0; ni < 4; ++ni) acc[mi][ni] = (f32x4)0.f;
    GEMM_TILE(acc, vp)
    float vb[4];
#pragma unroll
    for (int ni = 0; ni < 4; ++ni) vb[ni] = Vb[colbase + ni * 16 + lr];
#pragma unroll
    for (int r = 0; r < 8; ++r) {
      int mi = r >> 2, j = r & 3;
      float e = 0.f;
#pragma unroll
      for (int ni = 0; ni < 4; ++ni)
        e += __expf(acc[mi][ni][j] + vb[ni] - 8.f);
      s[r] += e;
    }
  }
#pragma unroll
  for (int off = 1; off < 16; off <<= 1)
#pragma unroll
    for (int r = 0; r < 8; ++r) s[r] += __shfl_xor(s[r], off, 64);

  if (lr == 0) {
#pragma unroll
    for (int r = 0; r < 8; ++r)
      red[w][(r >> 2) * 16 + hq * 4 + (r & 3)] = s[r];
  }
  __syncthreads();
  if (t < 32) {
    float S = 0.f;
#pragma unroll
    for (int ww = 0; ww < 16; ++ww) S += red[ww][t];
    lse_s[t] = 8.f + __logf(S);
  }
  __syncthreads();
  float lse_r[8];
#pragma unroll
  for (int r = 0; r < 8; ++r)
    lse_r[r] = lse_s[(r >> 2) * 16 + hq * 4 + (r & 3)];

  // ---- pass 2: recompute, subtract, store ----
  for (int c = 0; c < 8; ++c) {
    int colbase = c * 1024 + w * 64;
    if (colbase >= V_N) continue;
    const u16* vp = V2 + (size_t)(colbase >> 4) * 2048 + l * 8;
    f32x4 acc[2][4];
#pragma unroll
    for (int mi = 0; mi < 2; ++mi)
#pragma unroll
      for (int ni = 0; ni < 4; ++ni) acc[mi][ni] = (f32x4)0.f;
    GEMM_TILE(acc, vp)
    float vb[4];
#pragma unroll
    for (int ni = 0; ni < 4; ++ni) vb[ni] = Vb[colbase + ni * 16 + lr];
#pragma unroll
    for (int mi = 0; mi < 2; ++mi)
#pragma unroll
      for (int j = 0; j < 4; ++j) {
        size_t gr = (size_t)(rowbase + mi * 16 + hq * 4 + j);
#pragma unroll
        for (int ni = 0; ni < 4; ++ni)
          out[gr * V_N + colbase + ni * 16 + lr] =
              acc[mi][ni][j] + vb[ni] - lse_r[mi * 4 + j];
      }
  }
#undef GEMM_TILE
#undef MF
#undef VLD
}

extern "C" void kernel_launch(void* const* d_in, const int* in_sizes, int n_in,
                              void* d_out, int out_size, void* d_ws,
                              size_t ws_size, hipStream_t stream) {
  const float* x      = (const float*)d_in[0];
  const float* hidden = (const float*)d_in[1];
  const float* c_in   = (const float*)d_in[2];
  const float* Ui = (const float*)d_in[3];
  const float* Uf = (const float*)d_in[4];
  const float* Uo = (const float*)d_in[5];
  const float* Ug = (const float*)d_in[6];
  const float* Wi = (const float*)d_in[7];
  const float* Wf = (const float*)d_in[8];
  const float* Wo = (const float*)d_in[9];
  const float* Wg = (const float*)d_in[10];
  const float* Vw = (const float*)d_in[11];
  const float* Uib = (const float*)d_in[12];
  const float* Ufb = (const float*)d_in[13];
  const float* Uob = (const float*)d_in[14];
  const float* Ugb = (const float*)d_in[15];
  const float* Wib = (const float*)d_in[16];
  const float* Wfb = (const float*)d_in[17];
  const float* Wob = (const float*)d_in[18];
  const float* Wgb = (const float*)d_in[19];
  const float* Vb  = (const float*)d_in[20];

  float* out   = (float*)d_out;
  float* h_out = out + (size_t)B_N * V_N;
  float* c_out = h_out + (size_t)B_N * H_N;

  char* ws = (char*)d_ws;
  float* tailf = (float*)ws;  ws += (size_t)B_N * TW * 4;        // 6.3 MB
  u16* Wc = (u16*)ws;         ws += (size_t)NKT * 2048 * 16;     // 8.4 MB
  u16* V2 = (u16*)ws;         ws += (size_t)500 * 256 * 16;      // 2.0 MB
  u16* gates_p = (u16*)ws;    ws += (size_t)4 * B_N * NG * 2;    // 33.6 MB

  pack_tail_kernel<<<dim3(768), dim3(256), 0, stream>>>(hidden, tailf);
  pack_w_kernel<<<dim3(2048), dim3(256), 0, stream>>>(Ui, Uf, Uo, Ug,
                                                      Wi, Wf, Wo, Wg, Wc);
  pack_vw_kernel<<<dim3(500), dim3(256), 0, stream>>>(Vw, V2);

  gates_gemm_kernel<<<dim3(512), dim3(512), 0, stream>>>(
      x, tailf, Wc, gates_p);

  logits_lsm_kernel<<<dim3(256), dim3(1024), 0, stream>>>(
      gates_p, c_in, Uib, Ufb, Uob, Ugb, Wib, Wfb, Wob, Wgb,
      V2, Vb, h_out, c_out, out);
}